// Round 2
// baseline (1388.104 us; speedup 1.0000x reference)
//
#include <hip/hip_runtime.h>
#include <hip/hip_bf16.h>

#define NTOK 65536

typedef __attribute__((ext_vector_type(8))) short bf16x8;
typedef __attribute__((ext_vector_type(4))) float f32x4;

// ---- workspace byte offsets ----
constexpr size_t OFF_ACC  = 0;          // f32[16]: 0=hinge 1=nll 2=ediff 3=valid
constexpr size_t OFF_HIST = 64;         // int[136]: LabA,LabB,PredA,PredB
constexpr size_t ZERO_BYTES = 1024;
constexpr size_t OFF_SC   = 1024;                   // f32[65536]
constexpr size_t OFF_WBT  = OFF_SC  + 262144;       // ushort[589824] W_w^T bf16
constexpr size_t OFF_LSUM = OFF_WBT + 1179648;      // f32[589824]
constexpr size_t OFF_LSB  = OFF_LSUM + 2359296;     // ushort[589824] lsum bf16
constexpr size_t OFF_BCT  = OFF_LSB + 1179648;      // f32[68*768]  [cls_w | mat_local] col-major-by-output
constexpr size_t OFF_G2   = OFF_BCT + 208896;       // f32[768*34]
constexpr size_t OFF_G3   = OFF_G2 + 104448;        // f32[768*34]
constexpr size_t OFF_C0   = OFF_G3 + 104448;        // f32[34]
constexpr size_t OFF_CML0 = OFF_C0 + 256;           // f32[34]
constexpr size_t OFF_TD   = OFF_CML0 + 256;         // f32[65536]
constexpr size_t OFF_HEAD = OFF_TD + 262144;        // f32[512*768]
constexpr size_t OFF_XSUM = OFF_HEAD + 1572864;     // f32[512*768]
constexpr size_t OFF_Z    = OFF_XSUM + 1572864;     // f32[512*768]
constexpr size_t OFF_G    = OFF_Z + 1572864;        // f32[512*34]
constexpr size_t OFF_GML  = OFF_G + 69632;          // f32[512*34]
constexpr size_t OFF_PRED = OFF_GML + 69632;        // int[65536]
constexpr size_t OFF_P    = OFF_PRED + 262144;      // f32[65536*68]

__device__ __forceinline__ unsigned short f2bf(float f) {
  union { float f; unsigned int u; } v; v.f = f;
  unsigned int r = v.u + 0x7FFFu + ((v.u >> 16) & 1u);
  return (unsigned short)(r >> 16);
}

__device__ __forceinline__ bf16x8 pack8(const float* f) {
  union { unsigned short u[8]; bf16x8 v; } p;
#pragma unroll
  for (int i = 0; i < 8; ++i) p.u[i] = f2bf(f[i]);
  return p.v;
}

// ---------------- K1: weight prep (wbT, lsum, lsumb, bcT) ----------------
__global__ __launch_bounds__(256) void k_prep(
    const float* __restrict__ Ww, const float* __restrict__ linw,
    const float* __restrict__ clsw, const float* __restrict__ matl,
    unsigned short* __restrict__ wbT, float* __restrict__ lsum,
    unsigned short* __restrict__ lsumb, float* __restrict__ bcT) {
  int idx = blockIdx.x * 256 + threadIdx.x;
  if (idx < 589824) {                       // wbT[j][k] = bf16(Ww[k][j])
    int j = idx / 768, k = idx - j * 768;
    wbT[idx] = f2bf(Ww[k * 768 + j]);
  } else if (idx < 1179648) {
    int i = idx - 589824;
    float v = linw[i] + linw[589824 + i];
    lsum[i] = v; lsumb[i] = f2bf(v);
  } else {                                   // bcT[c][k], c<34: cls col, else matl row
    int i = idx - 1179648;                   // < 52224
    int c = i / 768, k = i - c * 768;
    bcT[i] = (c < 34) ? clsw[k * 34 + c] : matl[(c - 34) * 768 + k];
  }
}

// ---------------- K1b: c0/cml0 (bias-fold) ----------------
__global__ __launch_bounds__(64) void k_prep2(
    const float* __restrict__ clsw, const float* __restrict__ matl,
    const float* __restrict__ linb, const float* __restrict__ clsb,
    float* __restrict__ c0, float* __restrict__ cml0) {
  int b = blockIdx.x, t = threadIdx.x;
  float s = 0.f;
  if (b < 34) { for (int h = t; h < 768; h += 64) s = fmaf(linb[h], clsw[h * 34 + b], s); }
  else { int u = b - 34; for (int h = t; h < 768; h += 64) s = fmaf(linb[h], matl[u * 768 + h], s); }
  s += __shfl_xor(s, 1); s += __shfl_xor(s, 2); s += __shfl_xor(s, 4);
  s += __shfl_xor(s, 8); s += __shfl_xor(s, 16); s += __shfl_xor(s, 32);
  if (t == 0) { if (b < 34) c0[b] = clsb[b] + s; else cml0[b - 34] = s; }
}

// ---------------- K1c: duals G2 = lsum@cls_w, G3 = lsum@mat_local^T (f32) -------
__global__ __launch_bounds__(128) void k_dual(
    const float* __restrict__ lsum, const float* __restrict__ clsw,
    const float* __restrict__ matl, float* __restrict__ G2, float* __restrict__ G3) {
  int h = blockIdx.x, tid = threadIdx.x;
  __shared__ float ls[768];
  for (int i = tid; i < 768; i += 128) ls[i] = lsum[h * 768 + i];
  __syncthreads();
  int lane = tid & 63, w = tid >> 6;
  if (lane < 34) {
    float s = 0.f;
    if (w == 0) {
      for (int k = 0; k < 768; ++k) s = fmaf(ls[k], clsw[k * 34 + lane], s);
      G2[h * 34 + lane] = s;
    } else {
      for (int k = 0; k < 768; ++k) s = fmaf(ls[k], matl[lane * 768 + k], s);
      G3[h * 34 + lane] = s;
    }
  }
}

// ---------------- K2: MFMA GEMM 64 rows x 768 cols; MODE0: tanh-reduce->sscore,
//                  MODE1: store f32 -> out (z = head@lsum) ----------------
template<int MODE, int NI>
__global__ __launch_bounds__(256, 2) void k_mm(
    const float* __restrict__ A, const unsigned short* __restrict__ Bb,
    const float* __restrict__ Wb, const float* __restrict__ vw,
    float* __restrict__ out) {
  __shared__ unsigned short As[64 * 64];  // bf16, XOR-swizzled 16B units
  __shared__ float red[4 * 64];
  int tid = threadIdx.x, lane = tid & 63, wid = tid >> 6;
  int row0 = blockIdx.x * 64;
  int c0 = (blockIdx.y * 4 + wid) * (NI * 16);
  int sr = tid >> 2, kq = (tid & 3) * 16;
  const float* xsrc = A + (size_t)(row0 + sr) * 768 + kq;
  const unsigned short* bbase = Bb + (size_t)(c0 + (lane & 15)) * 768 + (lane >> 4) * 8;
  f32x4 acc[4][NI] = {};
  int swz = (sr & 7) << 4;
  char* asw = (char*)As + sr * 128;

  for (int kk = 0; kk < 768; kk += 64) {
    float fb[16];
    *(float4*)&fb[0]  = *(const float4*)(xsrc + kk);
    *(float4*)&fb[4]  = *(const float4*)(xsrc + kk + 4);
    *(float4*)&fb[8]  = *(const float4*)(xsrc + kk + 8);
    *(float4*)&fb[12] = *(const float4*)(xsrc + kk + 12);
    *(bf16x8*)(asw + ((2 * kq) ^ swz))      = pack8(&fb[0]);
    *(bf16x8*)(asw + ((2 * kq + 16) ^ swz)) = pack8(&fb[8]);
    __syncthreads();
#pragma unroll
    for (int ks = 0; ks < 2; ++ks) {
      bf16x8 a[4];
      int kb = ks * 64 + (lane >> 4) * 16;
#pragma unroll
      for (int mi = 0; mi < 4; ++mi) {
        int r = mi * 16 + (lane & 15);
        a[mi] = *(const bf16x8*)((const char*)As + r * 128 + (kb ^ ((r & 7) << 4)));
      }
#pragma unroll
      for (int ni = 0; ni < NI; ++ni) {
        bf16x8 b = *(const bf16x8*)(bbase + (size_t)ni * 16 * 768 + kk + ks * 32);
#pragma unroll
        for (int mi = 0; mi < 4; ++mi)
          acc[mi][ni] = __builtin_amdgcn_mfma_f32_16x16x32_bf16(a[mi], b, acc[mi][ni], 0, 0, 0);
      }
    }
    __syncthreads();
  }

  if (MODE == 0) {
    float sums[16];
#pragma unroll
    for (int i = 0; i < 16; ++i) sums[i] = 0.f;
#pragma unroll
    for (int ni = 0; ni < NI; ++ni) {
      int c = c0 + ni * 16 + (lane & 15);
      float wb = Wb[c], vv = vw[c];
#pragma unroll
      for (int mi = 0; mi < 4; ++mi)
#pragma unroll
        for (int reg = 0; reg < 4; ++reg) {
          float y = acc[mi][ni][reg] + wb;
          float e = __expf(2.f * y);               // tanh(y) = 1 - 2/(e^{2y}+1)
          sums[mi * 4 + reg] = fmaf(1.f - 2.f / (e + 1.f), vv, sums[mi * 4 + reg]);
        }
    }
#pragma unroll
    for (int i = 0; i < 16; ++i) {
      float v = sums[i];
      v += __shfl_xor(v, 1); v += __shfl_xor(v, 2); v += __shfl_xor(v, 4); v += __shfl_xor(v, 8);
      sums[i] = v;
    }
    if ((lane & 15) == 0) {
      int g = lane >> 4;
#pragma unroll
      for (int mi = 0; mi < 4; ++mi)
#pragma unroll
        for (int reg = 0; reg < 4; ++reg)
          red[wid * 64 + mi * 16 + g * 4 + reg] = sums[mi * 4 + reg];
    }
    __syncthreads();
    if (tid < 64) out[row0 + tid] = red[tid] + red[64 + tid] + red[128 + tid] + red[192 + tid];
  } else {
#pragma unroll
    for (int mi = 0; mi < 4; ++mi)
#pragma unroll
      for (int ni = 0; ni < NI; ++ni)
#pragma unroll
        for (int reg = 0; reg < 4; ++reg) {
          int r = row0 + mi * 16 + (lane >> 4) * 4 + reg;
          int c = c0 + ni * 16 + (lane & 15);
          out[(size_t)r * 768 + c] = acc[mi][ni][reg];
        }
  }
}

// ---------------- K3: softmax over S + head + xsum (H split x2) ----------------
__global__ __launch_bounds__(384) void k_softmax_head(
    const float* __restrict__ x, const float* __restrict__ sscore,
    const float* __restrict__ vb, float* __restrict__ td,
    float* __restrict__ head, float* __restrict__ xsum) {
  int n = blockIdx.x, half = blockIdx.y, tid = threadIdx.x;
  __shared__ float buf[128], tdl[128];
  float scv = 0.f;
  if (tid < 128) { scv = sscore[n * 128 + tid] + vb[0]; buf[tid] = scv; }
  __syncthreads();
  for (int w = 64; w >= 1; w >>= 1) {
    if (tid < w) buf[tid] = fmaxf(buf[tid], buf[tid + w]);
    __syncthreads();
  }
  float m = buf[0]; __syncthreads();
  float e = 0.f;
  if (tid < 128) { e = __expf(scv - m); buf[tid] = e; }
  __syncthreads();
  for (int w = 64; w >= 1; w >>= 1) {
    if (tid < w) buf[tid] += buf[tid + w];
    __syncthreads();
  }
  float ssum = buf[0];
  if (tid < 128) { float t = e / ssum; tdl[tid] = t; if (half == 0) td[n * 128 + tid] = t; }
  __syncthreads();
  int col = half * 384 + tid;
  float aH = 0.f, aX = 0.f;
  const float* xb = x + (size_t)n * 98304 + col;
  for (int s = 0; s < 128; ++s) {
    float v = xb[s * 768];
    aH = fmaf(tdl[s], v, aH); aX += v;
  }
  head[n * 768 + col] = aH;
  xsum[n * 768 + col] = aX;
}

// ---------------- K5: g = head@G2, gml = head@G3 (f32, argmax-safe) ----------------
__global__ __launch_bounds__(128) void k_gproj(
    const float* __restrict__ head, const float* __restrict__ G2,
    const float* __restrict__ G3, float* __restrict__ g, float* __restrict__ gml) {
  int n = blockIdx.x, tid = threadIdx.x;
  __shared__ float hs[768];
  for (int i = tid; i < 768; i += 128) hs[i] = head[n * 768 + i];
  __syncthreads();
  int lane = tid & 63, w = tid >> 6;
  if (lane < 34) {
    float s = 0.f;
    if (w == 0) {
      for (int h = 0; h < 768; ++h) s = fmaf(hs[h], G2[h * 34 + lane], s);
      g[n * 34 + lane] = s;
    } else {
      for (int h = 0; h < 768; ++h) s = fmaf(hs[h], G3[h * 34 + lane], s);
      gml[n * 34 + lane] = s;
    }
  }
}

// ---------------- K6: P = x @ bcT^T  (f32, B via wave-uniform scalar loads) -------
__global__ __launch_bounds__(256) void k_pgemm(
    const float* __restrict__ x, const float* __restrict__ bcT, float* __restrict__ P) {
  int tid = threadIdx.x;
  int lane = tid & 63;
  int w = __builtin_amdgcn_readfirstlane(tid >> 6);
  int row = blockIdx.x * 256 + w * 64 + lane;
  const float* xr = x + (size_t)row * 768;
  float acc[68];
#pragma unroll
  for (int c = 0; c < 68; ++c) acc[c] = 0.f;
  for (int kk = 0; kk < 768; kk += 16) {
    float a[16];
    *(float4*)&a[0]  = *(const float4*)(xr + kk);
    *(float4*)&a[4]  = *(const float4*)(xr + kk + 4);
    *(float4*)&a[8]  = *(const float4*)(xr + kk + 8);
    *(float4*)&a[12] = *(const float4*)(xr + kk + 12);
#pragma unroll
    for (int c = 0; c < 68; ++c) {
      const float* bp = bcT + (size_t)c * 768 + kk;   // wave-uniform -> s_load
      float s = acc[c];
#pragma unroll
      for (int j = 0; j < 16; ++j) s = fmaf(a[j], bp[j], s);
      acc[c] = s;
    }
  }
  float* pr = P + (size_t)row * 68;
#pragma unroll
  for (int c = 0; c < 68; ++c) pr[c] = acc[c];
}

// ---------------- K7: per-token logits/argmax/hinge/CE/energy-local/outputs -------
__global__ __launch_bounds__(128) void k_final(
    const float* __restrict__ P, const float* __restrict__ td,
    const int* __restrict__ labels, const int* __restrict__ padp,
    const float* __restrict__ g, const float* __restrict__ gml,
    const float* __restrict__ c0, const float* __restrict__ cml0,
    float* __restrict__ out, int* __restrict__ pred,
    float* __restrict__ accs, int* __restrict__ hist) {
  int n = blockIdx.x, s = threadIdx.x;
  int r = n * 128 + s;
  __shared__ float gs[34], gmls[34], c0s[34], cml0s[34];
  __shared__ float wred[2][4];
  if (s < 34) { gs[s] = g[n * 34 + s]; gmls[s] = gml[n * 34 + s]; c0s[s] = c0[s]; cml0s[s] = cml0[s]; }
  __syncthreads();
  float p[68];
  const float4* prow = (const float4*)(P + (size_t)r * 68);
#pragma unroll
  for (int i = 0; i < 17; ++i) {
    float4 v = prow[i];
    p[i * 4] = v.x; p[i * 4 + 1] = v.y; p[i * 4 + 2] = v.z; p[i * 4 + 3] = v.w;
  }
  float tds = td[r];
  int lab = labels[r];
  int pad = padp[0];
  float lg[34];
#pragma unroll
  for (int t = 0; t < 34; ++t) lg[t] = fmaxf(fmaf(tds, gs[t], p[t] + c0s[t]), 0.f);
  float best = lg[0]; int pidx = 0;
#pragma unroll
  for (int t = 1; t < 34; ++t) { if (lg[t] > best) { best = lg[t]; pidx = t; } }
  float* orow = out + 1 + (size_t)(r + 1) * 34;
#pragma unroll
  for (int t = 0; t < 34; ++t) orow[t] = lg[t];
  if (r == 0) {
#pragma unroll
    for (int t = 0; t < 34; ++t) out[1 + t] = lg[t];
  }
  if (r == NTOK - 1) {
#pragma unroll
    for (int t = 0; t < 34; ++t) out[1 + (size_t)(NTOK + 1) * 34 + t] = lg[t];
  }
  const size_t L2 = 1 + (size_t)(NTOK + 2) * 34;
  out[L2 + 1 + r] = (float)lab;
  if (r == 0) out[L2] = (float)lab;
  if (r == NTOK - 1) out[L2 + NTOK + 1] = (float)lab;
  float valid = (lab != pad) ? 1.f : 0.f;
  float sy = 0.f, pml_lab = 0.f, pml_pred = 0.f, so = -1e30f;
#pragma unroll
  for (int t = 0; t < 34; ++t) {
    bool il = (t == lab), ip = (t == pidx);
    sy = il ? lg[t] : sy;
    pml_lab = il ? p[34 + t] : pml_lab;
    pml_pred = ip ? p[34 + t] : pml_pred;
    so = fmaxf(so, il ? -1e30f : lg[t]);
  }
  float hl = fmaxf(0.f, 1.f + so - sy) * valid;
  float se = 0.f;
#pragma unroll
  for (int t = 0; t < 34; ++t) se += __expf(lg[t] - best);
  float nll = (best + logf(se) - sy) * valid;
  float elab = pml_lab + tds * gmls[lab] + cml0s[lab];
  float epred = pml_pred + tds * gmls[pidx] + cml0s[pidx];
  float ed = elab - epred;
  pred[r] = pidx;
  if (s == 126) { atomicAdd(&hist[lab], 1); atomicAdd(&hist[68 + pidx], 1); }
  if (s == 127) { atomicAdd(&hist[34 + lab], 1); atomicAdd(&hist[102 + pidx], 1); }
  float r0 = hl, r1 = nll, r2 = ed, r3 = valid;
#pragma unroll
  for (int d = 1; d < 64; d <<= 1) {
    r0 += __shfl_xor(r0, d); r1 += __shfl_xor(r1, d);
    r2 += __shfl_xor(r2, d); r3 += __shfl_xor(r3, d);
  }
  if ((s & 63) == 0) { wred[s >> 6][0] = r0; wred[s >> 6][1] = r1; wred[s >> 6][2] = r2; wred[s >> 6][3] = r3; }
  __syncthreads();
  if (s == 0) {
    atomicAdd(&accs[0], wred[0][0] + wred[1][0]);
    atomicAdd(&accs[1], wred[0][1] + wred[1][1]);
    atomicAdd(&accs[2], wred[0][2] + wred[1][2]);
    atomicAdd(&accs[3], wred[0][3] + wred[1][3]);
  }
}

// ---------------- K8: ste ----------------
__global__ __launch_bounds__(256) void k_ste(
    const float* __restrict__ x, const float* __restrict__ td,
    const int* __restrict__ pred, const int* __restrict__ padp,
    const float* __restrict__ xsum, const float* __restrict__ z,
    const float* __restrict__ linb, float* __restrict__ out) {
  int n = blockIdx.x, tid = threadIdx.x;
  __shared__ int bad[128];
  __shared__ float rb[256];
  int pad = padp[0];
  float tdv = 0.f, good = 0.f;
  if (tid < 128) {
    int pd = pred[n * 128 + tid];
    int isbad = (pd == pad);
    bad[tid] = isbad;
    if (!isbad) { tdv = td[n * 128 + tid]; good = 1.f; }
  }
  rb[tid] = tdv; __syncthreads();
  for (int w = 128; w >= 1; w >>= 1) { if (tid < w) rb[tid] += rb[tid + w]; __syncthreads(); }
  float tdm = rb[0]; __syncthreads();
  rb[tid] = good; __syncthreads();
  for (int w = 128; w >= 1; w >>= 1) { if (tid < w) rb[tid] += rb[tid + w]; __syncthreads(); }
  int cnt = (int)(rb[0] + 0.5f);
  __syncthreads();
  float a0 = xsum[n * 768 + tid], a1 = xsum[n * 768 + tid + 256], a2 = xsum[n * 768 + tid + 512];
  const float* xb = x + (size_t)n * 98304;
  for (int s = 0; s < 128; ++s) {
    if (bad[s]) {
      a0 -= xb[s * 768 + tid]; a1 -= xb[s * 768 + tid + 256]; a2 -= xb[s * 768 + tid + 512];
    }
  }
  const size_t L3 = 1 + (size_t)(NTOK + 2) * 34 + (NTOK + 2);
  float fc = (float)cnt;
  float accs3[3] = { a0, a1, a2 };
#pragma unroll
  for (int i = 0; i < 3; ++i) {
    int h = tid + i * 256;
    float val = 0.f;
    if (cnt > 0) val = (accs3[i] + tdm * z[n * 768 + h] + fc * linb[h]) / fc;
    out[L3 + (size_t)n * 768 + h] = val;
  }
}

// ---------------- K9: final scalar ----------------
__global__ __launch_bounds__(256) void k_loss(
    const float* __restrict__ accs, const int* __restrict__ hist,
    const float* __restrict__ matlab, float* __restrict__ out) {
  int tid = threadIdx.x;
  __shared__ float rb[256];
  float v = 0.f;
  for (int i = tid; i < 1156; i += 256) {
    int t = i / 34, u = i - t * 34;
    v += ((float)hist[t] * (float)hist[34 + u] - (float)hist[68 + t] * (float)hist[102 + u]) * matlab[i];
  }
  rb[tid] = v; __syncthreads();
  for (int w = 128; w >= 1; w >>= 1) { if (tid < w) rb[tid] += rb[tid + w]; __syncthreads(); }
  if (tid == 0) {
    float pair = rb[0];
    float nv = fmaxf(accs[3], 1.f);
    float hinge = accs[0] / nv;
    float ce = accs[1] / nv;
    float lte = fmaxf(0.f, hinge + accs[2] + pair);
    out[0] = lte + 0.5f * ce;
  }
}

extern "C" void kernel_launch(void* const* d_in, const int* in_sizes, int n_in,
                              void* d_out, int out_size, void* d_ws, size_t ws_size,
                              hipStream_t stream) {
  const float* x      = (const float*)d_in[0];
  const int*   labels = (const int*)d_in[1];
  const int*   padp   = (const int*)d_in[4];
  const float* Ww     = (const float*)d_in[6];
  const float* Wb     = (const float*)d_in[7];
  const float* vw     = (const float*)d_in[8];
  const float* vb     = (const float*)d_in[9];
  const float* clsw   = (const float*)d_in[10];
  const float* clsb   = (const float*)d_in[11];
  const float* matl   = (const float*)d_in[12];
  const float* matlab = (const float*)d_in[13];
  const float* linw   = (const float*)d_in[14];
  const float* linb   = (const float*)d_in[15];
  char* ws = (char*)d_ws;
  float* out = (float*)d_out;

  float*          accp   = (float*)(ws + OFF_ACC);
  int*            histp  = (int*)(ws + OFF_HIST);
  float*          sscore = (float*)(ws + OFF_SC);
  unsigned short* wbT    = (unsigned short*)(ws + OFF_WBT);
  float*          lsum   = (float*)(ws + OFF_LSUM);
  unsigned short* lsumb  = (unsigned short*)(ws + OFF_LSB);
  float*          bcT    = (float*)(ws + OFF_BCT);
  float*          G2p    = (float*)(ws + OFF_G2);
  float*          G3p    = (float*)(ws + OFF_G3);
  float*          c0p    = (float*)(ws + OFF_C0);
  float*          cml0p  = (float*)(ws + OFF_CML0);
  float*          tdp    = (float*)(ws + OFF_TD);
  float*          headp  = (float*)(ws + OFF_HEAD);
  float*          xsump  = (float*)(ws + OFF_XSUM);
  float*          zp     = (float*)(ws + OFF_Z);
  float*          gp     = (float*)(ws + OFF_G);
  float*          gmlp   = (float*)(ws + OFF_GML);
  int*            predp  = (int*)(ws + OFF_PRED);
  float*          Pp     = (float*)(ws + OFF_P);

  hipMemsetAsync(ws, 0, ZERO_BYTES, stream);
  k_prep<<<4812, 256, 0, stream>>>(Ww, linw, clsw, matl, wbT, lsum, lsumb, bcT);
  k_prep2<<<68, 64, 0, stream>>>(clsw, matl, linb, clsb, c0p, cml0p);
  k_dual<<<768, 128, 0, stream>>>(lsum, clsw, matl, G2p, G3p);
  k_mm<0, 12><<<dim3(1024, 1), 256, 0, stream>>>(x, wbT, Wb, vw, sscore);
  k_softmax_head<<<dim3(512, 2), 384, 0, stream>>>(x, sscore, vb, tdp, headp, xsump);
  k_mm<1, 3><<<dim3(8, 4), 256, 0, stream>>>(headp, lsumb, Wb, vw, zp);
  k_gproj<<<512, 128, 0, stream>>>(headp, G2p, G3p, gp, gmlp);
  k_pgemm<<<256, 256, 0, stream>>>(x, bcT, Pp);
  k_final<<<512, 128, 0, stream>>>(Pp, tdp, labels, padp, gp, gmlp, c0p, cml0p, out, predp, accp, histp);
  k_ste<<<512, 256, 0, stream>>>(x, tdp, predp, padp, xsump, zp, linb, out);
  k_loss<<<1, 256, 0, stream>>>(accp, histp, matlab, out);
}

// Round 5
// 742.312 us; speedup vs baseline: 1.8700x; 1.8700x over previous
//
#include <hip/hip_runtime.h>
#include <hip/hip_bf16.h>

#define NTOK 65536

typedef __attribute__((ext_vector_type(8))) short bf16x8;
typedef __attribute__((ext_vector_type(4))) float f32x4;

// ---- workspace byte offsets ----
constexpr size_t OFF_ACC  = 0;          // f32[16]: 0=hinge 1=nll 2=ediff 3=valid
constexpr size_t OFF_HIST = 64;         // int[136]: LabA,LabB,PredA,PredB
constexpr size_t ZERO_BYTES = 1024;
constexpr size_t OFF_SC   = 1024;                   // f32[65536]
constexpr size_t OFF_WBT  = OFF_SC  + 262144;       // ushort[589824] W_w^T bf16
constexpr size_t OFF_LSUM = OFF_WBT + 1179648;      // f32[589824]
constexpr size_t OFF_LSB  = OFF_LSUM + 2359296;     // ushort[589824] lsum bf16
constexpr size_t OFF_BH   = OFF_LSB + 1179648;      // ushort[80*768] B hi
constexpr size_t OFF_BL   = OFF_BH + 122880;        // ushort[80*768] B lo
constexpr size_t OFF_G2   = OFF_BL + 122880;        // f32[768*34]
constexpr size_t OFF_G3   = OFF_G2 + 104448;        // f32[768*34]
constexpr size_t OFF_C0   = OFF_G3 + 104448;        // f32[34]
constexpr size_t OFF_CML0 = OFF_C0 + 256;           // f32[34]
constexpr size_t OFF_TD   = OFF_CML0 + 256;         // f32[65536]
constexpr size_t OFF_HEAD = OFF_TD + 262144;        // f32[512*768]
constexpr size_t OFF_XSUM = OFF_HEAD + 1572864;     // f32[512*768]
constexpr size_t OFF_Z    = OFF_XSUM + 1572864;     // f32[512*768]
constexpr size_t OFF_G    = OFF_Z + 1572864;        // f32[512*34]
constexpr size_t OFF_GML  = OFF_G + 69632;          // f32[512*34]
constexpr size_t OFF_PRED = OFF_GML + 69632;        // int[65536]
constexpr size_t OFF_P    = OFF_PRED + 262144;      // f32[65536*68]

__device__ __forceinline__ unsigned short f2bf(float f) {
  union { float f; unsigned int u; } v; v.f = f;
  unsigned int r = v.u + 0x7FFFu + ((v.u >> 16) & 1u);
  return (unsigned short)(r >> 16);
}
__device__ __forceinline__ float bf2f(unsigned short h) {
  union { float f; unsigned int u; } v; v.u = ((unsigned int)h) << 16;
  return v.f;
}
__device__ __forceinline__ bf16x8 pack8(const float* f) {
  union { __hip_bfloat162 h[4]; bf16x8 v; } p;
#pragma unroll
  for (int i = 0; i < 4; ++i)
    p.h[i] = __float22bfloat162_rn(make_float2(f[2 * i], f[2 * i + 1]));
  return p.v;
}

// ---------------- K1a: tiled transpose Ww -> wbT (bf16) ----------------
__global__ __launch_bounds__(256) void k_trans(
    const float* __restrict__ Ww, unsigned short* __restrict__ wbT) {
  __shared__ float tile[64][65];
  int k0 = blockIdx.x * 64, j0 = blockIdx.y * 64;
  int tid = threadIdx.x;
#pragma unroll
  for (int i = 0; i < 16; ++i) {
    int e = i * 256 + tid;
    int r = e >> 6, c = e & 63;
    tile[r][c] = Ww[(size_t)(k0 + r) * 768 + j0 + c];
  }
  __syncthreads();
#pragma unroll
  for (int i = 0; i < 16; ++i) {
    int e = i * 256 + tid;
    int jr = e >> 6, kc = e & 63;
    wbT[(size_t)(j0 + jr) * 768 + k0 + kc] = f2bf(tile[kc][jr]);
  }
}

// ---------------- K1b: lsum/lsumb + B hi/lo split ----------------
__global__ __launch_bounds__(256) void k_prepB(
    const float* __restrict__ linw, const float* __restrict__ clsw,
    const float* __restrict__ matl, float* __restrict__ lsum,
    unsigned short* __restrict__ lsumb, unsigned short* __restrict__ BH,
    unsigned short* __restrict__ BL) {
  int idx = blockIdx.x * 256 + threadIdx.x;
  if (idx < 589824) {
    float v = linw[idx] + linw[589824 + idx];
    lsum[idx] = v; lsumb[idx] = f2bf(v);
  } else {
    int i = idx - 589824;                    // < 61440
    int c = i / 768, k = i - c * 768;
    float v = 0.f;
    if (c < 34) v = clsw[k * 34 + c];
    else if (c < 68) v = matl[(c - 34) * 768 + k];
    unsigned short hi = f2bf(v);
    BH[i] = hi;
    BL[i] = f2bf(v - bf2f(hi));
  }
}

// ---------------- K1c: c0/cml0 (bias-fold) ----------------
__global__ __launch_bounds__(64) void k_prep2(
    const float* __restrict__ clsw, const float* __restrict__ matl,
    const float* __restrict__ linb, const float* __restrict__ clsb,
    float* __restrict__ c0, float* __restrict__ cml0) {
  int b = blockIdx.x, t = threadIdx.x;
  float s = 0.f;
  if (b < 34) { for (int h = t; h < 768; h += 64) s = fmaf(linb[h], clsw[h * 34 + b], s); }
  else { int u = b - 34; for (int h = t; h < 768; h += 64) s = fmaf(linb[h], matl[u * 768 + h], s); }
  s += __shfl_xor(s, 1); s += __shfl_xor(s, 2); s += __shfl_xor(s, 4);
  s += __shfl_xor(s, 8); s += __shfl_xor(s, 16); s += __shfl_xor(s, 32);
  if (t == 0) { if (b < 34) c0[b] = clsb[b] + s; else cml0[b - 34] = s; }
}

// ---------------- K1d: duals G2 = lsum@cls_w, G3 = lsum@mat_local^T (f32) -------
__global__ __launch_bounds__(128) void k_dual(
    const float* __restrict__ lsum, const float* __restrict__ clsw,
    const float* __restrict__ matl, float* __restrict__ G2, float* __restrict__ G3) {
  int h = blockIdx.x, tid = threadIdx.x;
  __shared__ float ls[768];
  for (int i = tid; i < 768; i += 128) ls[i] = lsum[h * 768 + i];
  __syncthreads();
  int lane = tid & 63, w = tid >> 6;
  if (lane < 34) {
    float s = 0.f;
    if (w == 0) {
      for (int k = 0; k < 768; ++k) s = fmaf(ls[k], clsw[k * 34 + lane], s);
      G2[h * 34 + lane] = s;
    } else {
      for (int k = 0; k < 768; ++k) s = fmaf(ls[k], matl[lane * 768 + k], s);
      G3[h * 34 + lane] = s;
    }
  }
}

// ---------------- K2: MFMA GEMM 64 rows x 768 cols; MODE0: tanh-reduce->sscore,
//                  MODE1: store f32 -> out ----------------
template<int MODE, int NI>
__global__ __launch_bounds__(256, 2) void k_mm(
    const float* __restrict__ A, const unsigned short* __restrict__ Bb,
    const float* __restrict__ Wb, const float* __restrict__ vw,
    float* __restrict__ out) {
  __shared__ unsigned short As[64 * 64];  // bf16, XOR-swizzled 16B units
  __shared__ float red[4 * 64];
  int tid = threadIdx.x, lane = tid & 63, wid = tid >> 6;
  int row0 = blockIdx.x * 64;
  int c0 = (blockIdx.y * 4 + wid) * (NI * 16);
  int sr = tid >> 2, kq = (tid & 3) * 16;
  const float* xsrc = A + (size_t)(row0 + sr) * 768 + kq;
  const unsigned short* bbase = Bb + (size_t)(c0 + (lane & 15)) * 768 + (lane >> 4) * 8;
  f32x4 acc[4][NI] = {};
  int swz = (sr & 7) << 4;
  char* asw = (char*)As + sr * 128;

  for (int kk = 0; kk < 768; kk += 64) {
    float fb[16];
    *(float4*)&fb[0]  = *(const float4*)(xsrc + kk);
    *(float4*)&fb[4]  = *(const float4*)(xsrc + kk + 4);
    *(float4*)&fb[8]  = *(const float4*)(xsrc + kk + 8);
    *(float4*)&fb[12] = *(const float4*)(xsrc + kk + 12);
    *(bf16x8*)(asw + ((2 * kq) ^ swz))      = pack8(&fb[0]);
    *(bf16x8*)(asw + ((2 * kq + 16) ^ swz)) = pack8(&fb[8]);
    __syncthreads();
#pragma unroll
    for (int ks = 0; ks < 2; ++ks) {
      bf16x8 a[4];
      int kb = ks * 64 + (lane >> 4) * 16;
#pragma unroll
      for (int mi = 0; mi < 4; ++mi) {
        int r = mi * 16 + (lane & 15);
        a[mi] = *(const bf16x8*)((const char*)As + r * 128 + (kb ^ ((r & 7) << 4)));
      }
#pragma unroll
      for (int ni = 0; ni < NI; ++ni) {
        bf16x8 b = *(const bf16x8*)(bbase + (size_t)ni * 16 * 768 + kk + ks * 32);
#pragma unroll
        for (int mi = 0; mi < 4; ++mi)
          acc[mi][ni] = __builtin_amdgcn_mfma_f32_16x16x32_bf16(a[mi], b, acc[mi][ni], 0, 0, 0);
      }
    }
    __syncthreads();
  }

  if (MODE == 0) {
    float sums[16];
#pragma unroll
    for (int i = 0; i < 16; ++i) sums[i] = 0.f;
#pragma unroll
    for (int ni = 0; ni < NI; ++ni) {
      int c = c0 + ni * 16 + (lane & 15);
      float wb = Wb[c], vv = vw[c];
#pragma unroll
      for (int mi = 0; mi < 4; ++mi)
#pragma unroll
        for (int reg = 0; reg < 4; ++reg) {
          float y = acc[mi][ni][reg] + wb;
          float e = __expf(2.f * y);               // tanh(y) = 1 - 2/(e^{2y}+1)
          sums[mi * 4 + reg] = fmaf(1.f - 2.f / (e + 1.f), vv, sums[mi * 4 + reg]);
        }
    }
#pragma unroll
    for (int i = 0; i < 16; ++i) {
      float v = sums[i];
      v += __shfl_xor(v, 1); v += __shfl_xor(v, 2); v += __shfl_xor(v, 4); v += __shfl_xor(v, 8);
      sums[i] = v;
    }
    if ((lane & 15) == 0) {
      int g = lane >> 4;
#pragma unroll
      for (int mi = 0; mi < 4; ++mi)
#pragma unroll
        for (int reg = 0; reg < 4; ++reg)
          red[wid * 64 + mi * 16 + g * 4 + reg] = sums[mi * 4 + reg];
    }
    __syncthreads();
    if (tid < 64) out[row0 + tid] = red[tid] + red[64 + tid] + red[128 + tid] + red[192 + tid];
  } else {
#pragma unroll
    for (int mi = 0; mi < 4; ++mi)
#pragma unroll
      for (int ni = 0; ni < NI; ++ni)
#pragma unroll
        for (int reg = 0; reg < 4; ++reg) {
          int r = row0 + mi * 16 + (lane >> 4) * 4 + reg;
          int c = c0 + ni * 16 + (lane & 15);
          out[(size_t)r * 768 + c] = acc[mi][ni][reg];
        }
  }
}

// ---------------- K3: softmax over S + head + xsum (H split x2) ----------------
__global__ __launch_bounds__(384) void k_softmax_head(
    const float* __restrict__ x, const float* __restrict__ sscore,
    const float* __restrict__ vb, float* __restrict__ td,
    float* __restrict__ head, float* __restrict__ xsum) {
  int n = blockIdx.x, half = blockIdx.y, tid = threadIdx.x;
  __shared__ float buf[128], tdl[128];
  float scv = 0.f;
  if (tid < 128) { scv = sscore[n * 128 + tid] + vb[0]; buf[tid] = scv; }
  __syncthreads();
  for (int w = 64; w >= 1; w >>= 1) {
    if (tid < w) buf[tid] = fmaxf(buf[tid], buf[tid + w]);
    __syncthreads();
  }
  float m = buf[0]; __syncthreads();
  float e = 0.f;
  if (tid < 128) { e = __expf(scv - m); buf[tid] = e; }
  __syncthreads();
  for (int w = 64; w >= 1; w >>= 1) {
    if (tid < w) buf[tid] += buf[tid + w];
    __syncthreads();
  }
  float ssum = buf[0];
  if (tid < 128) { float t = e / ssum; tdl[tid] = t; if (half == 0) td[n * 128 + tid] = t; }
  __syncthreads();
  int col = half * 384 + tid;
  float aH = 0.f, aX = 0.f;
  const float* xb = x + (size_t)n * 98304 + col;
  for (int s = 0; s < 128; ++s) {
    float v = xb[s * 768];
    aH = fmaf(tdl[s], v, aH); aX += v;
  }
  head[n * 768 + col] = aH;
  xsum[n * 768 + col] = aX;
}

// ---------------- K5: g = head@G2, gml = head@G3 (f32, argmax-safe) ----------------
__global__ __launch_bounds__(128) void k_gproj(
    const float* __restrict__ head, const float* __restrict__ G2,
    const float* __restrict__ G3, float* __restrict__ g, float* __restrict__ gml) {
  int n = blockIdx.x, tid = threadIdx.x;
  __shared__ float hs[768];
  for (int i = tid; i < 768; i += 128) hs[i] = head[n * 768 + i];
  __syncthreads();
  int lane = tid & 63, w = tid >> 6;
  if (lane < 34) {
    float s = 0.f;
    if (w == 0) {
      for (int h = 0; h < 768; ++h) s = fmaf(hs[h], G2[h * 34 + lane], s);
      g[n * 34 + lane] = s;
    } else {
      for (int h = 0; h < 768; ++h) s = fmaf(hs[h], G3[h * 34 + lane], s);
      gml[n * 34 + lane] = s;
    }
  }
}

// ---------------- K6: P = x @ B^T via split-bf16 MFMA (near-f32 precision) -------
__global__ __launch_bounds__(256) void k_pmm(
    const float* __restrict__ x, const unsigned short* __restrict__ BH,
    const unsigned short* __restrict__ BL, float* __restrict__ P) {
  __shared__ unsigned short AsH[64 * 64];
  __shared__ unsigned short AsL[64 * 64];
  int tid = threadIdx.x, lane = tid & 63, wid = tid >> 6;
  int row0 = blockIdx.x * 64;
  int sr = tid >> 2, kq = (tid & 3) * 16;
  const float* xsrc = x + (size_t)(row0 + sr) * 768 + kq;
  const unsigned short* bbH = BH + (size_t)(lane & 15) * 768 + (lane >> 4) * 8;
  const unsigned short* bbL = BL + (size_t)(lane & 15) * 768 + (lane >> 4) * 8;
  f32x4 acc[5] = {};
  int swz = (sr & 7) << 4;
  char* aswH = (char*)AsH + sr * 128;
  char* aswL = (char*)AsL + sr * 128;
  int arow = wid * 16 + (lane & 15);
  const char* arH = (const char*)AsH + arow * 128;
  const char* arL = (const char*)AsL + arow * 128;
  int aswz = (arow & 7) << 4;

  for (int kk = 0; kk < 768; kk += 64) {
    float fb[16];
    *(float4*)&fb[0]  = *(const float4*)(xsrc + kk);
    *(float4*)&fb[4]  = *(const float4*)(xsrc + kk + 4);
    *(float4*)&fb[8]  = *(const float4*)(xsrc + kk + 8);
    *(float4*)&fb[12] = *(const float4*)(xsrc + kk + 12);
    union { unsigned short u[8]; bf16x8 v; } h0, h1, l0, l1;
#pragma unroll
    for (int i = 0; i < 8; ++i) {
      h0.u[i] = f2bf(fb[i]);        l0.u[i] = f2bf(fb[i] - bf2f(h0.u[i]));
      h1.u[i] = f2bf(fb[8 + i]);    l1.u[i] = f2bf(fb[8 + i] - bf2f(h1.u[i]));
    }
    *(bf16x8*)(aswH + ((2 * kq) ^ swz))      = h0.v;
    *(bf16x8*)(aswH + ((2 * kq + 16) ^ swz)) = h1.v;
    *(bf16x8*)(aswL + ((2 * kq) ^ swz))      = l0.v;
    *(bf16x8*)(aswL + ((2 * kq + 16) ^ swz)) = l1.v;
    __syncthreads();
#pragma unroll
    for (int ks = 0; ks < 2; ++ks) {
      int kb = (ks * 64 + (lane >> 4) * 16) ^ aswz;
      bf16x8 aH = *(const bf16x8*)(arH + kb);
      bf16x8 aL = *(const bf16x8*)(arL + kb);
#pragma unroll
      for (int ni = 0; ni < 5; ++ni) {
        bf16x8 bH = *(const bf16x8*)(bbH + (size_t)ni * 16 * 768 + kk + ks * 32);
        bf16x8 bL = *(const bf16x8*)(bbL + (size_t)ni * 16 * 768 + kk + ks * 32);
        acc[ni] = __builtin_amdgcn_mfma_f32_16x16x32_bf16(aH, bH, acc[ni], 0, 0, 0);
        acc[ni] = __builtin_amdgcn_mfma_f32_16x16x32_bf16(aH, bL, acc[ni], 0, 0, 0);
        acc[ni] = __builtin_amdgcn_mfma_f32_16x16x32_bf16(aL, bH, acc[ni], 0, 0, 0);
      }
    }
    __syncthreads();
  }
  int rb = row0 + wid * 16 + (lane >> 4) * 4;
#pragma unroll
  for (int ni = 0; ni < 5; ++ni) {
    int c = ni * 16 + (lane & 15);
    if (c < 68) {
#pragma unroll
      for (int reg = 0; reg < 4; ++reg)
        P[(size_t)(rb + reg) * 68 + c] = acc[ni][reg];
    }
  }
}

// ---------------- K7: per-token logits/argmax/hinge/CE/energy-local/outputs -------
__global__ __launch_bounds__(128) void k_final(
    const float* __restrict__ P, const float* __restrict__ td,
    const int* __restrict__ labels, const int* __restrict__ padp,
    const float* __restrict__ g, const float* __restrict__ gml,
    const float* __restrict__ c0, const float* __restrict__ cml0,
    float* __restrict__ out, int* __restrict__ pred,
    float* __restrict__ accs, int* __restrict__ hist) {
  int n = blockIdx.x, s = threadIdx.x;
  int r = n * 128 + s;
  __shared__ float gs[34], gmls[34], c0s[34], cml0s[34];
  __shared__ float wred[2][4];
  if (s < 34) { gs[s] = g[n * 34 + s]; gmls[s] = gml[n * 34 + s]; c0s[s] = c0[s]; cml0s[s] = cml0[s]; }
  __syncthreads();
  float p[68];
  const float4* prow = (const float4*)(P + (size_t)r * 68);
#pragma unroll
  for (int i = 0; i < 17; ++i) {
    float4 v = prow[i];
    p[i * 4] = v.x; p[i * 4 + 1] = v.y; p[i * 4 + 2] = v.z; p[i * 4 + 3] = v.w;
  }
  float tds = td[r];
  int lab = labels[r];
  int pad = padp[0];
  float lg[34];
#pragma unroll
  for (int t = 0; t < 34; ++t) lg[t] = fmaxf(fmaf(tds, gs[t], p[t] + c0s[t]), 0.f);
  float best = lg[0]; int pidx = 0;
#pragma unroll
  for (int t = 1; t < 34; ++t) { if (lg[t] > best) { best = lg[t]; pidx = t; } }
  float* orow = out + 1 + (size_t)(r + 1) * 34;
#pragma unroll
  for (int t = 0; t < 34; ++t) orow[t] = lg[t];
  if (r == 0) {
#pragma unroll
    for (int t = 0; t < 34; ++t) out[1 + t] = lg[t];
  }
  if (r == NTOK - 1) {
#pragma unroll
    for (int t = 0; t < 34; ++t) out[1 + (size_t)(NTOK + 1) * 34 + t] = lg[t];
  }
  const size_t L2 = 1 + (size_t)(NTOK + 2) * 34;
  out[L2 + 1 + r] = (float)lab;
  if (r == 0) out[L2] = (float)lab;
  if (r == NTOK - 1) out[L2 + NTOK + 1] = (float)lab;
  float valid = (lab != pad) ? 1.f : 0.f;
  float sy = 0.f, pml_lab = 0.f, pml_pred = 0.f, so = -1e30f;
#pragma unroll
  for (int t = 0; t < 34; ++t) {
    bool il = (t == lab), ip = (t == pidx);
    sy = il ? lg[t] : sy;
    pml_lab = il ? p[34 + t] : pml_lab;
    pml_pred = ip ? p[34 + t] : pml_pred;
    so = fmaxf(so, il ? -1e30f : lg[t]);
  }
  float hl = fmaxf(0.f, 1.f + so - sy) * valid;
  float se = 0.f;
#pragma unroll
  for (int t = 0; t < 34; ++t) se += __expf(lg[t] - best);
  float nll = (best + logf(se) - sy) * valid;
  float elab = pml_lab + tds * gmls[lab] + cml0s[lab];
  float epred = pml_pred + tds * gmls[pidx] + cml0s[pidx];
  float ed = elab - epred;
  pred[r] = pidx;
  if (s == 126) { atomicAdd(&hist[lab], 1); atomicAdd(&hist[68 + pidx], 1); }
  if (s == 127) { atomicAdd(&hist[34 + lab], 1); atomicAdd(&hist[102 + pidx], 1); }
  float r0 = hl, r1 = nll, r2 = ed, r3 = valid;
#pragma unroll
  for (int d = 1; d < 64; d <<= 1) {
    r0 += __shfl_xor(r0, d); r1 += __shfl_xor(r1, d);
    r2 += __shfl_xor(r2, d); r3 += __shfl_xor(r3, d);
  }
  if ((s & 63) == 0) { wred[s >> 6][0] = r0; wred[s >> 6][1] = r1; wred[s >> 6][2] = r2; wred[s >> 6][3] = r3; }
  __syncthreads();
  if (s == 0) {
    atomicAdd(&accs[0], wred[0][0] + wred[1][0]);
    atomicAdd(&accs[1], wred[0][1] + wred[1][1]);
    atomicAdd(&accs[2], wred[0][2] + wred[1][2]);
    atomicAdd(&accs[3], wred[0][3] + wred[1][3]);
  }
}

// ---------------- K8: ste (gather only bad rows) ----------------
__global__ __launch_bounds__(256) void k_ste(
    const float* __restrict__ x, const float* __restrict__ td,
    const int* __restrict__ pred, const int* __restrict__ padp,
    const float* __restrict__ xsum, const float* __restrict__ z,
    const float* __restrict__ linb, float* __restrict__ out) {
  int n = blockIdx.x, tid = threadIdx.x;
  __shared__ int badlist[128];
  __shared__ int nbadsh;
  __shared__ float rb[256];
  if (tid == 0) nbadsh = 0;
  __syncthreads();
  int pad = padp[0];
  float tdv = 0.f, good = 0.f;
  if (tid < 128) {
    int pd = pred[n * 128 + tid];
    if (pd == pad) {
      int slot = atomicAdd(&nbadsh, 1);
      badlist[slot] = tid;
    } else { tdv = td[n * 128 + tid]; good = 1.f; }
  }
  rb[tid] = tdv; __syncthreads();
  for (int w = 128; w >= 1; w >>= 1) { if (tid < w) rb[tid] += rb[tid + w]; __syncthreads(); }
  float tdm = rb[0]; __syncthreads();
  rb[tid] = good; __syncthreads();
  for (int w = 128; w >= 1; w >>= 1) { if (tid < w) rb[tid] += rb[tid + w]; __syncthreads(); }
  int cnt = (int)(rb[0] + 0.5f);
  int nbad = nbadsh;
  float a0 = xsum[n * 768 + tid], a1 = xsum[n * 768 + tid + 256], a2 = xsum[n * 768 + tid + 512];
  const float* xb = x + (size_t)n * 98304;
  for (int i = 0; i < nbad; ++i) {
    int s = badlist[i];
    a0 -= xb[s * 768 + tid]; a1 -= xb[s * 768 + tid + 256]; a2 -= xb[s * 768 + tid + 512];
  }
  const size_t L3 = 1 + (size_t)(NTOK + 2) * 34 + (NTOK + 2);
  float fc = (float)cnt;
  float accs3[3] = { a0, a1, a2 };
#pragma unroll
  for (int i = 0; i < 3; ++i) {
    int h = tid + i * 256;
    float val = 0.f;
    if (cnt > 0) val = (accs3[i] + tdm * z[n * 768 + h] + fc * linb[h]) / fc;
    out[L3 + (size_t)n * 768 + h] = val;
  }
}

// ---------------- K9: final scalar ----------------
__global__ __launch_bounds__(256) void k_loss(
    const float* __restrict__ accs, const int* __restrict__ hist,
    const float* __restrict__ matlab, float* __restrict__ out) {
  int tid = threadIdx.x;
  __shared__ float rb[256];
  float v = 0.f;
  for (int i = tid; i < 1156; i += 256) {
    int t = i / 34, u = i - t * 34;
    v += ((float)hist[t] * (float)hist[34 + u] - (float)hist[68 + t] * (float)hist[102 + u]) * matlab[i];
  }
  rb[tid] = v; __syncthreads();
  for (int w = 128; w >= 1; w >>= 1) { if (tid < w) rb[tid] += rb[tid + w]; __syncthreads(); }
  if (tid == 0) {
    float pair = rb[0];
    float nv = fmaxf(accs[3], 1.f);
    float hinge = accs[0] / nv;
    float ce = accs[1] / nv;
    float lte = fmaxf(0.f, hinge + accs[2] + pair);
    out[0] = lte + 0.5f * ce;
  }
}

extern "C" void kernel_launch(void* const* d_in, const int* in_sizes, int n_in,
                              void* d_out, int out_size, void* d_ws, size_t ws_size,
                              hipStream_t stream) {
  const float* x      = (const float*)d_in[0];
  const int*   labels = (const int*)d_in[1];
  const int*   padp   = (const int*)d_in[4];
  const float* Ww     = (const float*)d_in[6];
  const float* Wb     = (const float*)d_in[7];
  const float* vw     = (const float*)d_in[8];
  const float* vb     = (const float*)d_in[9];
  const float* clsw   = (const float*)d_in[10];
  const float* clsb   = (const float*)d_in[11];
  const float* matl   = (const float*)d_in[12];
  const float* matlab = (const float*)d_in[13];
  const float* linw   = (const float*)d_in[14];
  const float* linb   = (const float*)d_in[15];
  char* ws = (char*)d_ws;
  float* out = (float*)d_out;

  float*          accp   = (float*)(ws + OFF_ACC);
  int*            histp  = (int*)(ws + OFF_HIST);
  float*          sscore = (float*)(ws + OFF_SC);
  unsigned short* wbT    = (unsigned short*)(ws + OFF_WBT);
  float*          lsum   = (float*)(ws + OFF_LSUM);
  unsigned short* lsumb  = (unsigned short*)(ws + OFF_LSB);
  unsigned short* BHp    = (unsigned short*)(ws + OFF_BH);
  unsigned short* BLp    = (unsigned short*)(ws + OFF_BL);
  float*          G2p    = (float*)(ws + OFF_G2);
  float*          G3p    = (float*)(ws + OFF_G3);
  float*          c0p    = (float*)(ws + OFF_C0);
  float*          cml0p  = (float*)(ws + OFF_CML0);
  float*          tdp    = (float*)(ws + OFF_TD);
  float*          headp  = (float*)(ws + OFF_HEAD);
  float*          xsump  = (float*)(ws + OFF_XSUM);
  float*          zp     = (float*)(ws + OFF_Z);
  float*          gp     = (float*)(ws + OFF_G);
  float*          gmlp   = (float*)(ws + OFF_GML);
  int*            predp  = (int*)(ws + OFF_PRED);
  float*          Pp     = (float*)(ws + OFF_P);

  hipMemsetAsync(ws, 0, ZERO_BYTES, stream);
  k_trans<<<dim3(12, 12), 256, 0, stream>>>(Ww, wbT);
  k_prepB<<<2544, 256, 0, stream>>>(linw, clsw, matl, lsum, lsumb, BHp, BLp);
  k_prep2<<<68, 64, 0, stream>>>(clsw, matl, linb, clsb, c0p, cml0p);
  k_dual<<<768, 128, 0, stream>>>(lsum, clsw, matl, G2p, G3p);
  k_mm<0, 12><<<dim3(1024, 1), 256, 0, stream>>>(x, wbT, Wb, vw, sscore);
  k_softmax_head<<<dim3(512, 2), 384, 0, stream>>>(x, sscore, vb, tdp, headp, xsump);
  k_mm<1, 3><<<dim3(8, 4), 256, 0, stream>>>(headp, lsumb, Wb, vw, zp);
  k_gproj<<<512, 128, 0, stream>>>(headp, G2p, G3p, gp, gmlp);
  k_pmm<<<1024, 256, 0, stream>>>(x, BHp, BLp, Pp);
  k_final<<<512, 128, 0, stream>>>(Pp, tdp, labels, padp, gp, gmlp, c0p, cml0p, out, predp, accp, histp);
  k_ste<<<512, 256, 0, stream>>>(x, tdp, predp, padp, xsump, zp, linb, out);
  k_loss<<<1, 256, 0, stream>>>(accp, histp, matlab, out);
}